// Round 9
// baseline (692.697 us; speedup 1.0000x reference)
//
#include <hip/hip_runtime.h>

#define N 8192
#define DIN 512
#define DOUT 256
#define ALPHA 0.2f
#define NEG_INF -9.0e15f

typedef __attribute__((ext_vector_type(8))) short bf16x8;
typedef __attribute__((ext_vector_type(4))) float f32x4;
typedef __attribute__((ext_vector_type(4))) int   i32x4;

__device__ __forceinline__ unsigned f2bf_u(float f) {
    unsigned u = __builtin_bit_cast(unsigned, f);
    return (u + 0x7fffu + ((u >> 16) & 1u)) >> 16;   // RNE bf16
}
__device__ __forceinline__ unsigned pack2bf(float lo, float hi) {
    return f2bf_u(lo) | (f2bf_u(hi) << 16);
}
union U4BF8 { uint4 u; bf16x8 v; };

// Kernel 0: W fp32 [512][256] -> WB bf16 in MFMA-B layout ((k>>3)*256+c)*8+(k&7).
__global__ __launch_bounds__(256) void wb_kernel(const float* __restrict__ W,
                                                 ushort* __restrict__ WB) {
    const int g = blockIdx.x * 256 + threadIdx.x;   // 64*256 = 16384
    const int c = g & 255, k8 = g >> 8;
    const float* wp = W + (size_t)(k8 * 8) * DOUT + c;
    U4BF8 o;
    o.u.x = pack2bf(wp[0 * DOUT], wp[1 * DOUT]);
    o.u.y = pack2bf(wp[2 * DOUT], wp[3 * DOUT]);
    o.u.z = pack2bf(wp[4 * DOUT], wp[5 * DOUT]);
    o.u.w = pack2bf(wp[6 * DOUT], wp[7 * DOUT]);
    *(uint4*)(WB + (size_t)g * 8) = o.u;
}

// Kernel 1: h = X@W + b via MFMA, split-K across 4 waves (unchanged from R0).
__global__ __launch_bounds__(256) void h_kernel(
        const float* __restrict__ X, const ushort* __restrict__ WB,
        const float* __restrict__ bvec, const float* __restrict__ a,
        ushort* __restrict__ hB, float* __restrict__ el, float* __restrict__ er)
{
    __shared__ float red[4][64][65];
    __shared__ float elr[2][4][16];
    const int t = threadIdx.x;
    const int w = t >> 6, l = t & 63, q = l >> 4, n = l & 15;
    const int i0 = blockIdx.x * 16;
    f32x4 acc[16];
    #pragma unroll
    for (int ct = 0; ct < 16; ++ct) acc[ct] = (f32x4){0.f, 0.f, 0.f, 0.f};
    const float* xp = X + (size_t)(i0 + n) * DIN + q * 8;

    #pragma unroll
    for (int ks = 0; ks < 4; ++ks) {
        const int k0 = w * 128 + ks * 32;
        const float4 x0 = *(const float4*)(xp + k0);
        const float4 x1 = *(const float4*)(xp + k0 + 4);
        U4BF8 pa;
        pa.u.x = pack2bf(x0.x, x0.y); pa.u.y = pack2bf(x0.z, x0.w);
        pa.u.z = pack2bf(x1.x, x1.y); pa.u.w = pack2bf(x1.z, x1.w);
        const ushort* wbp = WB + ((k0 >> 3) + q) * 2048 + n * 8;
        bf16x8 bfr[16];
        #pragma unroll
        for (int ct = 0; ct < 16; ++ct) bfr[ct] = *(const bf16x8*)(wbp + ct * 128);
        #pragma unroll
        for (int ct = 0; ct < 16; ++ct)
            acc[ct] = __builtin_amdgcn_mfma_f32_16x16x32_bf16(pa.v, bfr[ct], acc[ct], 0, 0, 0);
    }
    #pragma unroll
    for (int ct = 0; ct < 16; ++ct)
        #pragma unroll
        for (int r = 0; r < 4; ++r) red[w][l][ct * 4 + r] = acc[ct][r];
    __syncthreads();

    float pl[4] = {0.f, 0.f, 0.f, 0.f}, pr[4] = {0.f, 0.f, 0.f, 0.f};
    const int hbase = (blockIdx.x * 2 + (q >> 1)) * 2048 + n * 8 + (q & 1) * 4;
    #pragma unroll
    for (int c2 = 0; c2 < 4; ++c2) {
        const int ct = w * 4 + c2;
        const float bb = bvec[ct * 16 + n];
        const float al = a[ct * 16 + n];
        const float ar = a[DOUT + ct * 16 + n];
        float v[4];
        #pragma unroll
        for (int r = 0; r < 4; ++r) {
            v[r] = red[0][l][ct * 4 + r] + red[1][l][ct * 4 + r]
                 + red[2][l][ct * 4 + r] + red[3][l][ct * 4 + r] + bb;
            pl[r] += v[r] * al;
            pr[r] += v[r] * ar;
        }
        ushort4 hp;
        hp.x = (ushort)f2bf_u(v[0]); hp.y = (ushort)f2bf_u(v[1]);
        hp.z = (ushort)f2bf_u(v[2]); hp.w = (ushort)f2bf_u(v[3]);
        *(ushort4*)&hB[hbase + ct * 128] = hp;
    }
    #pragma unroll
    for (int r = 0; r < 4; ++r) {
        #pragma unroll
        for (int off = 1; off < 16; off <<= 1) {
            pl[r] += __shfl_xor(pl[r], off);
            pr[r] += __shfl_xor(pr[r], off);
        }
    }
    if (n == 0) {
        #pragma unroll
        for (int r = 0; r < 4; ++r) {
            elr[0][w][q * 4 + r] = pl[r];
            elr[1][w][q * 4 + r] = pr[r];
        }
    }
    __syncthreads();
    if (t < 16) {
        el[i0 + t] = elr[0][0][t] + elr[0][1][t] + elr[0][2][t] + elr[0][3][t];
        er[i0 + t] = elr[1][0][t] + elr[1][1][t] + elr[1][2][t] + elr[1][3][t];
    }
}

// 8 masked-exp lanes -> one packed A-fragment word-group + running sum.
#define EXP8(ELM, E0, E1, M0, M1, PA, LS)                                          \
    {                                                                              \
        float v, p0, p1, p2, p3, p4, p5, p6, p7;                                   \
        v = ELM + E0.x; v = fmaxf(v, ALPHA * v); p0 = __expf(M0.x > 0 ? v : NEG_INF); \
        v = ELM + E0.y; v = fmaxf(v, ALPHA * v); p1 = __expf(M0.y > 0 ? v : NEG_INF); \
        v = ELM + E0.z; v = fmaxf(v, ALPHA * v); p2 = __expf(M0.z > 0 ? v : NEG_INF); \
        v = ELM + E0.w; v = fmaxf(v, ALPHA * v); p3 = __expf(M0.w > 0 ? v : NEG_INF); \
        v = ELM + E1.x; v = fmaxf(v, ALPHA * v); p4 = __expf(M1.x > 0 ? v : NEG_INF); \
        v = ELM + E1.y; v = fmaxf(v, ALPHA * v); p5 = __expf(M1.y > 0 ? v : NEG_INF); \
        v = ELM + E1.z; v = fmaxf(v, ALPHA * v); p6 = __expf(M1.z > 0 ? v : NEG_INF); \
        v = ELM + E1.w; v = fmaxf(v, ALPHA * v); p7 = __expf(M1.w > 0 ? v : NEG_INF); \
        LS += p0 + p1 + p2 + p3 + p4 + p5 + p6 + p7;                               \
        PA.u.x = pack2bf(p0, p1); PA.u.y = pack2bf(p2, p3);                        \
        PA.u.z = pack2bf(p4, p5); PA.u.w = pack2bf(p6, p7);                        \
    }

// Kernel 2 (v10, free-run): NO LDS staging, NO in-loop barriers. hB B-fragments
// are read directly from global (hB = 4 MB, XCD-L2-resident; adj uses
// nontemporal loads so the 256 MB adj stream doesn't evict it). Every wave
// streams independently: adj -> exp/pack -> 32 global b128 + 32 MFMA per step;
// phases of different waves overlap on the CU (no lockstep). Block = 256 thr
// (4 waves x 16 rows), grid = 128 rb x 4 jq = 512; LDS = 8 KB ers only.
// Compute mapping identical to R0 (16x16x32, verified).
__global__ __launch_bounds__(256, 4) void attn_kernel(
        const int* __restrict__ adj, const float* __restrict__ el,
        const float* __restrict__ er, const float* __restrict__ ab,
        const ushort* __restrict__ hB, float* __restrict__ pout,
        float* __restrict__ plsum)
{
    __shared__ float ers[2048];          // 8 KB: er j-quarter
    const int t = threadIdx.x;
    const int w = t >> 6, l = t & 63, q = l >> 4, n = l & 15;
    const int rb = blockIdx.x >> 2, jq = blockIdx.x & 3;
    const int j0 = jq * 2048;
    const int row = rb * 64 + w * 16 + n;
    const float elm = el[row] + ab[0];
    const int* alp = adj + (size_t)row * N + j0 + q * 8;

    f32x4 acc[16];
    #pragma unroll
    for (int ct = 0; ct < 16; ++ct) acc[ct] = (f32x4){0.f, 0.f, 0.f, 0.f};
    float lsum = 0.f;

    // prologue: er quarter -> LDS (single barrier of the kernel)
    *(float4*)&ers[t * 8]     = *(const float4*)&er[j0 + t * 8];
    *(float4*)&ers[t * 8 + 4] = *(const float4*)&er[j0 + t * 8 + 4];
    __syncthreads();

    // adj regs for step 0 (16 ints/lane: 2 k-groups of 32 j)
    i32x4 am0 = __builtin_nontemporal_load((const i32x4*)(alp + 0));
    i32x4 am1 = __builtin_nontemporal_load((const i32x4*)(alp + 4));
    i32x4 am2 = __builtin_nontemporal_load((const i32x4*)(alp + 32));
    i32x4 am3 = __builtin_nontemporal_load((const i32x4*)(alp + 36));

    for (int s = 0; s < 32; ++s) {       // 32 steps of 64 j, barrier-free
        U4BF8 pa0, pa1;
        {
            const float4 e00 = *(const float4*)&ers[s * 64 + q * 8];
            const float4 e01 = *(const float4*)&ers[s * 64 + q * 8 + 4];
            EXP8(elm, e00, e01, am0, am1, pa0, lsum);
            const float4 e10 = *(const float4*)&ers[s * 64 + 32 + q * 8];
            const float4 e11 = *(const float4*)&ers[s * 64 + 32 + q * 8 + 4];
            EXP8(elm, e10, e11, am2, am3, pa1, lsum);
        }
        if (s < 31) {                    // adj for s+1; latency hides under MFMA phase + TLP
            const int* ap = alp + (s + 1) * 64;
            am0 = __builtin_nontemporal_load((const i32x4*)(ap + 0));
            am1 = __builtin_nontemporal_load((const i32x4*)(ap + 4));
            am2 = __builtin_nontemporal_load((const i32x4*)(ap + 32));
            am3 = __builtin_nontemporal_load((const i32x4*)(ap + 36));
        }
        // B-fragments straight from global/L2. hB row index (j>>3) =
        // jq*256 + s*8 + kg*4 + q; within row: col block ct*128 + n*8.
        const ushort* bp0 = hB + (size_t)(jq * 256 + s * 8 + q) * 2048 + n * 8;
        const ushort* bp1 = bp0 + (size_t)4 * 2048;
        #pragma unroll
        for (int ct = 0; ct < 16; ++ct) {
            const bf16x8 bf = *(const bf16x8*)(bp0 + ct * 128);
            acc[ct] = __builtin_amdgcn_mfma_f32_16x16x32_bf16(pa0.v, bf, acc[ct], 0, 0, 0);
        }
        #pragma unroll
        for (int ct = 0; ct < 16; ++ct) {
            const bf16x8 bf = *(const bf16x8*)(bp1 + ct * 128);
            acc[ct] = __builtin_amdgcn_mfma_f32_16x16x32_bf16(pa1.v, bf, acc[ct], 0, 0, 0);
        }
    }

    // row sums: the 4 q-groups hold the same row n
    lsum += __shfl_xor(lsum, 16);
    lsum += __shfl_xor(lsum, 32);
    if (l < 16) plsum[(size_t)jq * N + row] = lsum;

    // unnormalized partial tile: row rb*64 + w*16 + q*4 + r, col ct*16 + n
    float* pb = pout + ((size_t)jq * N + rb * 64 + w * 16 + q * 4) * 256 + n;
    #pragma unroll
    for (int ct = 0; ct < 16; ++ct)
        #pragma unroll
        for (int r = 0; r < 4; ++r)
            __builtin_nontemporal_store(acc[ct][r], pb + (size_t)r * 256 + ct * 16);
}

// Kernel 3: combine j-quarter partials + normalize (R0 version). grid 2048 x 256.
__global__ __launch_bounds__(256) void combine_kernel(
        const float* __restrict__ pout, const float* __restrict__ plsum,
        float* __restrict__ out)
{
    const int t = threadIdx.x;
    const int row = blockIdx.x * 4 + (t >> 6);
    const int c = (t & 63) * 4;
    const size_t idx = (size_t)row * 256 + c;
    const size_t qs = (size_t)N * 256;
    float4 v0 = *(const float4*)&pout[idx];
    float4 v1 = *(const float4*)&pout[idx + qs];
    float4 v2 = *(const float4*)&pout[idx + 2 * qs];
    float4 v3 = *(const float4*)&pout[idx + 3 * qs];
    const float li = 1.0f / (plsum[row] + plsum[N + row]
                           + plsum[2 * N + row] + plsum[3 * N + row]);
    float4 o;
    o.x = (v0.x + v1.x + v2.x + v3.x) * li;
    o.y = (v0.y + v1.y + v2.y + v3.y) * li;
    o.z = (v0.z + v1.z + v2.z + v3.z) * li;
    o.w = (v0.w + v1.w + v2.w + v3.w) * li;
    *(float4*)&out[idx] = o;
}

extern "C" void kernel_launch(void* const* d_in, const int* in_sizes, int n_in,
                              void* d_out, int out_size, void* d_ws, size_t ws_size,
                              hipStream_t stream) {
    const int*   adj = (const int*)  d_in[0];
    const float* X   = (const float*)d_in[1];
    const float* W   = (const float*)d_in[2];
    const float* b   = (const float*)d_in[3];
    const float* a   = (const float*)d_in[4];
    const float* ab  = (const float*)d_in[5];
    float* out = (float*)d_out;

    ushort* hB    = (ushort*)d_ws;                        // 4 MB
    ushort* WB    = hB + (size_t)N * DOUT;                // 256 KB
    float*  el    = (float*)(WB + (size_t)DIN * DOUT);    // 32 KB
    float*  er    = el + N;                               // 32 KB
    float*  plsum = er + N;                               // 4*N fp32 = 128 KB
    float*  pout  = plsum + 4 * N;                        // 4*N*256 fp32 = 32 MB

    wb_kernel<<<dim3(64), dim3(256), 0, stream>>>(W, WB);
    h_kernel<<<dim3(N / 16), dim3(256), 0, stream>>>(X, WB, b, a, hB, el, er);
    attn_kernel<<<dim3(512), dim3(256), 0, stream>>>(adj, el, er, ab, hB, pout, plsum);
    combine_kernel<<<dim3(N / 4), dim3(256), 0, stream>>>(pout, plsum, out);
}